// Round 5
// baseline (83.273 us; speedup 1.0000x reference)
//
#include <hip/hip_runtime.h>

#define HH 64
#define WW 64
#define PIN 64
#define POUT 64
#define NFEAT 54

typedef _Float16 half8 __attribute__((ext_vector_type(8)));
typedef _Float16 half4 __attribute__((ext_vector_type(4)));
typedef float f32x4 __attribute__((ext_vector_type(4)));

// ---------------- filter prep ----------------
// Fprep[f][o][c] fp16, f enumerates (k,l): k=0,l=1..9 (linear, coef F[0,l]+F[l,0]);
// k=1..9, l=k..9 (quad, coef F[k,l]+F[l,k], diag F[k,k]). Fconst[o] = bias + sum_c F[o,c,0,0].
__global__ void prep_filters(const float* __restrict__ f, const float* __restrict__ bias,
                             _Float16* __restrict__ fprep, float* __restrict__ fconst) {
    int blk = blockIdx.x;
    if (blk == NFEAT) {
        int o = threadIdx.x;
        if (o < POUT) {
            float s = bias[o];
            for (int c = 0; c < PIN; ++c) s += f[(size_t)(o * PIN + c) * 100];
            fconst[o] = s;
        }
        return;
    }
    // decode feature id -> (k,l)
    int k = 0, l = 0, cnt = 0;
    for (int kk = 0; kk <= 9; ++kk) {
        int ls = (kk == 0) ? 1 : kk;
        for (int ll = ls; ll <= 9; ++ll) {
            if (cnt == blk) { k = kk; l = ll; }
            ++cnt;
        }
    }
    for (int i = threadIdx.x; i < POUT * PIN; i += blockDim.x) {
        int o = i >> 6, c = i & 63;
        const float* fc = f + (size_t)(o * PIN + c) * 100;
        float v;
        if (k == 0)      v = fc[l] + fc[l * 10];
        else if (k == l) v = fc[k * 10 + k];
        else             v = fc[k * 10 + l] + fc[l * 10 + k];
        fprep[((size_t)blk * POUT + o) * PIN + c] = (_Float16)v;
    }
}

// ---------------- main MFMA kernel ----------------
// block = 2 output rows x 64 w = 256 pixels, 4 waves: wave w covers row (w>>1), w-half (w&1)*32.
// Wave tile: 32 m x 64 n, 16x16x32 f16 MFMA, K = 64 channels split in 2 kc halves.
__global__ __launch_bounds__(256) void poly2d_mfma(
    const float* __restrict__ x, const _Float16* __restrict__ fprep,
    const float* __restrict__ fconst, float* __restrict__ out)
{
    __shared__ __align__(16) char smem[33792]; // x tile [4][66][8cg swz][8 f16]; reused as out stage [128][65] f32

    const int t = threadIdx.x;
    const int bid = blockIdx.x;
    const int b = bid >> 5;
    const int h0 = (bid & 31) * 2;

    // ---- stage x tile (rows h0-1..h0+2, w -1..64, all 64 c) as swizzled fp16 ----
    {
        const int w = t & 63;
        const int cq = (t >> 6) * 4;
        for (int h = 0; h < 4; ++h) {
            int h_in = h0 - 1 + h;
            bool hok = ((unsigned)h_in < HH);
            #pragma unroll
            for (int cc = 0; cc < 4; ++cc) {
                int c = cq + cc * 16;
                float v0 = 0.f, v1 = 0.f, v2 = 0.f, v3 = 0.f;
                if (hok) {
                    const float* gx = x + (((size_t)b * PIN + c) * HH + h_in) * WW + w;
                    v0 = gx[0]; v1 = gx[4096]; v2 = gx[2 * 4096]; v3 = gx[3 * 4096];
                }
                half4 pk = {(_Float16)v0, (_Float16)v1, (_Float16)v2, (_Float16)v3};
                int wl = w + 1;
                int byte = ((h * 66 + wl) * 8 + ((c >> 3) ^ (wl & 7))) * 16 + (c & 7) * 2;
                *(half4*)(smem + byte) = pk;
            }
        }
        if (t < 64) { // w halo (input w=-1 and w=64 are always out of image -> zero)
            int h = t & 3, side = (t >> 2) & 1, cg = t >> 3;
            int wl = side ? 65 : 0;
            int byte = ((h * 66 + wl) * 8 + (cg ^ (wl & 7))) * 16;
            f32x4 z = {0.f, 0.f, 0.f, 0.f};
            *(f32x4*)(smem + byte) = z;
        }
    }
    __syncthreads();

    const int wid = t >> 6;
    const int lane = t & 63;
    const int hh = wid >> 1;           // output row within block (0/1)
    const int wbase = (wid & 1) * 32;  // w half
    const int ln15 = lane & 15;
    const int lq = lane >> 4;          // 0..3

    f32x4 acc[2][4] = {};

    #pragma unroll
    for (int kc = 0; kc < 2; ++kc) {
        // load 9 shift panels + ones into registers (frag: m=ln15, k=lq*8+j)
        half8 xp[10][2];
        #pragma unroll
        for (int mb = 0; mb < 2; ++mb) {
            half8 ones = {(_Float16)1.f, (_Float16)1.f, (_Float16)1.f, (_Float16)1.f,
                          (_Float16)1.f, (_Float16)1.f, (_Float16)1.f, (_Float16)1.f};
            xp[0][mb] = ones;
        }
        #pragma unroll
        for (int p = 1; p <= 9; ++p) {
            const int dh = (p - 1) / 3 - 1, dw = (p - 1) % 3 - 1;
            #pragma unroll
            for (int mb = 0; mb < 2; ++mb) {
                int wpix = wbase + mb * 16 + ln15;
                int wl = wpix + dw + 1;
                int hidx = hh + dh + 1;
                int cg = kc * 4 + lq;
                int byte = ((hidx * 66 + wl) * 8 + (cg ^ (wl & 7))) * 16;
                xp[p][mb] = *(const half8*)(smem + byte);
            }
        }
        // B-frag ring prefetch (depth 2) straight from global (L2-resident Fprep)
        half8 Bbuf[3][4];
        const _Float16* fb = fprep + ln15 * 64 + lq * 8 + kc * 32;
        #pragma unroll
        for (int nb = 0; nb < 4; ++nb) Bbuf[0][nb] = *(const half8*)(fb + nb * 1024);
        #pragma unroll
        for (int nb = 0; nb < 4; ++nb) Bbuf[1][nb] = *(const half8*)(fb + 4096 + nb * 1024);

        int fidx = 0;
        #pragma unroll
        for (int k = 0; k <= 9; ++k) {
            #pragma unroll
            for (int l = (k == 0 ? 1 : k); l <= 9; ++l) {
                const int f = fidx;
                if (f + 2 < NFEAT) {
                    #pragma unroll
                    for (int nb = 0; nb < 4; ++nb)
                        Bbuf[(f + 2) % 3][nb] =
                            *(const half8*)(fb + (size_t)(f + 2) * 4096 + nb * 1024);
                }
                half8 prod0 = xp[k][0] * xp[l][0];
                half8 prod1 = xp[k][1] * xp[l][1];
                #pragma unroll
                for (int nb = 0; nb < 4; ++nb) {
                    acc[0][nb] = __builtin_amdgcn_mfma_f32_16x16x32_f16(
                        prod0, Bbuf[f % 3][nb], acc[0][nb], 0, 0, 0);
                    acc[1][nb] = __builtin_amdgcn_mfma_f32_16x16x32_f16(
                        prod1, Bbuf[f % 3][nb], acc[1][nb], 0, 0, 0);
                }
                ++fidx;
            }
        }
    }

    __syncthreads(); // everyone done reading x tile; reuse smem for output transpose
    float* os = (float*)smem; // [128 m][65]
    #pragma unroll
    for (int mb = 0; mb < 2; ++mb)
        #pragma unroll
        for (int nb = 0; nb < 4; ++nb)
            #pragma unroll
            for (int j = 0; j < 4; ++j) {
                int m = wid * 32 + mb * 16 + lq * 4 + j; // C/D: row=(lane>>4)*4+reg
                int o = nb * 16 + ln15;                  //      col=lane&15
                os[m * 65 + o] = acc[mb][nb][j];
            }
    __syncthreads();

    { // coalesced store: lanes sweep w
        const int w = t & 63;
        const int og = t >> 6;
        #pragma unroll
        for (int h2 = 0; h2 < 2; ++h2) {
            #pragma unroll
            for (int oo = 0; oo < 16; ++oo) {
                int o = og * 16 + oo;
                int m = (h2 * 2 + (w >> 5)) * 32 + (w & 31);
                float val = os[m * 65 + o] + fconst[o];
                out[(((size_t)b * POUT + o) * HH + (h0 + h2)) * WW + w] = val;
            }
        }
    }
}

// ---------------- fp32 fallback (round-1 kernel), used only if ws too small ----------------
__global__ __launch_bounds__(256) void poly2d_fp32(
    const float* __restrict__ x, const float* __restrict__ f,
    const float* __restrict__ bias, float* __restrict__ out)
{
    const int t = threadIdx.x;
    const int wo = t & 63;
    const int ho = (blockIdx.x & 15) * 4 + (t >> 6);
    const int o = (blockIdx.x >> 4) & 63;
    const int b = blockIdx.x >> 10;

    float acc = bias[o];
    const float* xb = x + (size_t)b * PIN * HH * WW;
    const float* fo = f + (size_t)o * PIN * 100;
    for (int c = 0; c < PIN; ++c) {
        const float* xc = xb + (size_t)c * HH * WW;
        float s[10];
        s[0] = 1.0f;
        #pragma unroll
        for (int kh = 0; kh < 3; ++kh) {
            int h = ho - 1 + kh;
            bool hok = ((unsigned)h < HH);
            #pragma unroll
            for (int kw = 0; kw < 3; ++kw) {
                int w = wo - 1 + kw;
                s[1 + kh * 3 + kw] = (hok && (unsigned)w < WW) ? xc[h * WW + w] : 0.0f;
            }
        }
        const float* fc = fo + c * 100;
        #pragma unroll
        for (int i = 0; i < 10; ++i) {
            float wsum = 0.0f;
            #pragma unroll
            for (int j = 0; j < 10; ++j) wsum = fmaf(fc[i * 10 + j], s[j], wsum);
            acc = fmaf(wsum, s[i], acc);
        }
    }
    out[(((size_t)b * POUT + o) * HH + ho) * WW + wo] = acc;
}

extern "C" void kernel_launch(void* const* d_in, const int* in_sizes, int n_in,
                              void* d_out, int out_size, void* d_ws, size_t ws_size,
                              hipStream_t stream) {
    const float* x    = (const float*)d_in[0];
    const float* filt = (const float*)d_in[1];
    const float* bias = (const float*)d_in[2];
    float* out = (float*)d_out;

    const size_t FPREP_BYTES = (size_t)NFEAT * POUT * PIN * 2; // 442368
    if (ws_size < FPREP_BYTES + 256) {
        poly2d_fp32<<<dim3(8 * 64 * 16), dim3(256), 0, stream>>>(x, filt, bias, out);
        return;
    }
    _Float16* fprep = (_Float16*)d_ws;
    float* fconst = (float*)((char*)d_ws + FPREP_BYTES);

    prep_filters<<<dim3(NFEAT + 1), dim3(256), 0, stream>>>(filt, bias, fprep, fconst);
    poly2d_mfma<<<dim3(256), dim3(256), 0, stream>>>(x, fprep, fconst, out);
}

// Round 6
// 63.766 us; speedup vs baseline: 1.3059x; 1.3059x over previous
//
#include <hip/hip_runtime.h>

#define HH 64
#define WW 64
#define PIN 64
#define POUT 64
#define NFEAT 54

typedef _Float16 half8 __attribute__((ext_vector_type(8)));
typedef _Float16 half4 __attribute__((ext_vector_type(4)));
typedef float f32x4 __attribute__((ext_vector_type(4)));

// ---------------- filter prep ----------------
// Fprep[f][o][c] fp16, f enumerates (k,l): k=0,l=1..9 (linear, coef F[0,l]+F[l,0]);
// k=1..9, l=k..9 (quad, coef F[k,l]+F[l,k], diag F[k,k]). Fconst[o] = bias + sum_c F[o,c,0,0].
// 4 blocks per feature for parallelism; block NFEAT*4 does fconst.
__global__ void prep_filters(const float* __restrict__ f, const float* __restrict__ bias,
                             _Float16* __restrict__ fprep, float* __restrict__ fconst) {
    int blk = blockIdx.x;
    if (blk == NFEAT * 4) {
        int o = threadIdx.x;
        if (o < POUT) {
            float s = bias[o];
            for (int c = 0; c < PIN; ++c) s += f[(size_t)(o * PIN + c) * 100];
            fconst[o] = s;
        }
        return;
    }
    int feat = blk >> 2, part = blk & 3;
    // decode feature id -> (k,l)
    int k = 0, l = 0, cnt = 0;
    for (int kk = 0; kk <= 9; ++kk) {
        int ls = (kk == 0) ? 1 : kk;
        for (int ll = ls; ll <= 9; ++ll) {
            if (cnt == feat) { k = kk; l = ll; }
            ++cnt;
        }
    }
    int iend = (part + 1) * 1024;
    for (int i = part * 1024 + threadIdx.x; i < iend; i += 256) {
        int o = i >> 6, c = i & 63;
        const float* fc = f + (size_t)(o * PIN + c) * 100;
        float v;
        if (k == 0)      v = fc[l] + fc[l * 10];
        else if (k == l) v = fc[k * 10 + k];
        else             v = fc[k * 10 + l] + fc[l * 10 + k];
        fprep[((size_t)feat * POUT + o) * PIN + c] = (_Float16)v;
    }
}

// ---------------- main MFMA kernel ----------------
// block = 512 threads = 8 waves. Wave wid: kc = wid>>2 (channel half), mwid = wid&3
// selects m-tile (row hh = mwid>>1, w-half = mwid&1). Wave tile: 32m x 64n, one kc.
// kc halves reduced through LDS f32 epilogue stage.
__global__ __launch_bounds__(512, 2) void poly2d_mfma(
    const float* __restrict__ x, const _Float16* __restrict__ fprep,
    const float* __restrict__ fconst, float* __restrict__ out)
{
    __shared__ __align__(16) char smem[33792]; // x tile [4][66][8cg swz][8 f16]; reused as out stage [128][65] f32

    const int t = threadIdx.x;
    const int bid = blockIdx.x;
    const int b = bid >> 5;
    const int h0 = (bid & 31) * 2;

    // ---- stage x tile (rows h0-1..h0+2, w -1..64, all 64 c) as swizzled fp16 ----
    {
        const int w = t & 63;
        const int g = t >> 6;              // 0..7
        #pragma unroll
        for (int h = 0; h < 4; ++h) {
            int h_in = h0 - 1 + h;
            bool hok = ((unsigned)h_in < HH);
            #pragma unroll
            for (int cc = 0; cc < 2; ++cc) {
                int c = g * 4 + cc * 32;   // channels c..c+3
                float v0 = 0.f, v1 = 0.f, v2 = 0.f, v3 = 0.f;
                if (hok) {
                    const float* gx = x + (((size_t)b * PIN + c) * HH + h_in) * WW + w;
                    v0 = gx[0]; v1 = gx[4096]; v2 = gx[2 * 4096]; v3 = gx[3 * 4096];
                }
                half4 pk = {(_Float16)v0, (_Float16)v1, (_Float16)v2, (_Float16)v3};
                int wl = w + 1;
                int byte = ((h * 66 + wl) * 8 + ((c >> 3) ^ (wl & 7))) * 16 + (c & 7) * 2;
                *(half4*)(smem + byte) = pk;
            }
        }
        if (t < 64) { // w halo (input w=-1 and w=64 are out of image -> zero)
            int h = t & 3, side = (t >> 2) & 1, cg = t >> 3;
            int wl = side ? 65 : 0;
            int byte = ((h * 66 + wl) * 8 + (cg ^ (wl & 7))) * 16;
            f32x4 z = {0.f, 0.f, 0.f, 0.f};
            *(f32x4*)(smem + byte) = z;
        }
    }
    __syncthreads();

    const int wid = t >> 6;            // 0..7
    const int lane = t & 63;
    const int kc = wid >> 2;           // channel half handled by this wave
    const int mwid = wid & 3;          // m-tile index within block
    const int hh = mwid >> 1;          // output row within block (0/1)
    const int wbase = (mwid & 1) * 32; // w half
    const int ln15 = lane & 15;
    const int lq = lane >> 4;          // 0..3

    f32x4 acc[2][4] = {};

    // load 9 shift panels + ones into registers (frag: m=ln15, k=lq*8+j)
    half8 xp[10][2];
    {
        half8 ones = {(_Float16)1.f, (_Float16)1.f, (_Float16)1.f, (_Float16)1.f,
                      (_Float16)1.f, (_Float16)1.f, (_Float16)1.f, (_Float16)1.f};
        xp[0][0] = ones; xp[0][1] = ones;
    }
    #pragma unroll
    for (int p = 1; p <= 9; ++p) {
        const int dh = (p - 1) / 3 - 1, dw = (p - 1) % 3 - 1;
        #pragma unroll
        for (int mb = 0; mb < 2; ++mb) {
            int wpix = wbase + mb * 16 + ln15;
            int wl = wpix + dw + 1;
            int hidx = hh + dh + 1;
            int cg = kc * 4 + lq;
            int byte = ((hidx * 66 + wl) * 8 + (cg ^ (wl & 7))) * 16;
            xp[p][mb] = *(const half8*)(smem + byte);
        }
    }

    // B-frag ring prefetch (depth 4, 3 features ahead) straight from global (L2-resident Fprep)
    half8 Bbuf[4][4];
    const _Float16* fb = fprep + ln15 * 64 + lq * 8 + kc * 32;
    #pragma unroll
    for (int s = 0; s < 3; ++s)
        #pragma unroll
        for (int nb = 0; nb < 4; ++nb)
            Bbuf[s][nb] = *(const half8*)(fb + (size_t)s * 4096 + nb * 1024);

    int fidx = 0;
    #pragma unroll
    for (int k = 0; k <= 9; ++k) {
        #pragma unroll
        for (int l = (k == 0 ? 1 : k); l <= 9; ++l) {
            const int f = fidx;
            if (f + 3 < NFEAT) {
                #pragma unroll
                for (int nb = 0; nb < 4; ++nb)
                    Bbuf[(f + 3) & 3][nb] =
                        *(const half8*)(fb + (size_t)(f + 3) * 4096 + nb * 1024);
            }
            half8 prod0 = xp[k][0] * xp[l][0];
            half8 prod1 = xp[k][1] * xp[l][1];
            #pragma unroll
            for (int nb = 0; nb < 4; ++nb) {
                acc[0][nb] = __builtin_amdgcn_mfma_f32_16x16x32_f16(
                    prod0, Bbuf[f & 3][nb], acc[0][nb], 0, 0, 0);
                acc[1][nb] = __builtin_amdgcn_mfma_f32_16x16x32_f16(
                    prod1, Bbuf[f & 3][nb], acc[1][nb], 0, 0, 0);
            }
            ++fidx;
        }
    }

    __syncthreads(); // everyone done reading x tile; reuse smem for output stage
    float* os = (float*)smem; // [128 m][65]
    if (kc == 0) {
        #pragma unroll
        for (int mb = 0; mb < 2; ++mb)
            #pragma unroll
            for (int nb = 0; nb < 4; ++nb)
                #pragma unroll
                for (int j = 0; j < 4; ++j) {
                    int m = mwid * 32 + mb * 16 + lq * 4 + j; // C/D: row=(lane>>4)*4+reg
                    int o = nb * 16 + ln15;                   //      col=lane&15
                    os[m * 65 + o] = acc[mb][nb][j];
                }
    }
    __syncthreads();
    if (kc == 1) {
        #pragma unroll
        for (int mb = 0; mb < 2; ++mb)
            #pragma unroll
            for (int nb = 0; nb < 4; ++nb)
                #pragma unroll
                for (int j = 0; j < 4; ++j) {
                    int m = mwid * 32 + mb * 16 + lq * 4 + j;
                    int o = nb * 16 + ln15;
                    os[m * 65 + o] += acc[mb][nb][j];
                }
    }
    __syncthreads();

    { // coalesced store: lanes sweep w
        const int w = t & 63;
        const int og = t >> 6; // 0..7
        #pragma unroll
        for (int h2 = 0; h2 < 2; ++h2) {
            #pragma unroll
            for (int oo = 0; oo < 8; ++oo) {
                int o = og * 8 + oo;
                int m = (h2 * 2 + (w >> 5)) * 32 + (w & 31);
                float val = os[m * 65 + o] + fconst[o];
                out[(((size_t)b * POUT + o) * HH + (h0 + h2)) * WW + w] = val;
            }
        }
    }
}

// ---------------- fp32 fallback, used only if ws too small ----------------
__global__ __launch_bounds__(256) void poly2d_fp32(
    const float* __restrict__ x, const float* __restrict__ f,
    const float* __restrict__ bias, float* __restrict__ out)
{
    const int t = threadIdx.x;
    const int wo = t & 63;
    const int ho = (blockIdx.x & 15) * 4 + (t >> 6);
    const int o = (blockIdx.x >> 4) & 63;
    const int b = blockIdx.x >> 10;

    float acc = bias[o];
    const float* xb = x + (size_t)b * PIN * HH * WW;
    const float* fo = f + (size_t)o * PIN * 100;
    for (int c = 0; c < PIN; ++c) {
        const float* xc = xb + (size_t)c * HH * WW;
        float s[10];
        s[0] = 1.0f;
        #pragma unroll
        for (int kh = 0; kh < 3; ++kh) {
            int h = ho - 1 + kh;
            bool hok = ((unsigned)h < HH);
            #pragma unroll
            for (int kw = 0; kw < 3; ++kw) {
                int w = wo - 1 + kw;
                s[1 + kh * 3 + kw] = (hok && (unsigned)w < WW) ? xc[h * WW + w] : 0.0f;
            }
        }
        const float* fc = fo + c * 100;
        #pragma unroll
        for (int i = 0; i < 10; ++i) {
            float wsum = 0.0f;
            #pragma unroll
            for (int j = 0; j < 10; ++j) wsum = fmaf(fc[i * 10 + j], s[j], wsum);
            acc = fmaf(wsum, s[i], acc);
        }
    }
    out[(((size_t)b * POUT + o) * HH + ho) * WW + wo] = acc;
}

extern "C" void kernel_launch(void* const* d_in, const int* in_sizes, int n_in,
                              void* d_out, int out_size, void* d_ws, size_t ws_size,
                              hipStream_t stream) {
    const float* x    = (const float*)d_in[0];
    const float* filt = (const float*)d_in[1];
    const float* bias = (const float*)d_in[2];
    float* out = (float*)d_out;

    const size_t FPREP_BYTES = (size_t)NFEAT * POUT * PIN * 2; // 442368
    if (ws_size < FPREP_BYTES + 256) {
        poly2d_fp32<<<dim3(8 * 64 * 16), dim3(256), 0, stream>>>(x, filt, bias, out);
        return;
    }
    _Float16* fprep = (_Float16*)d_ws;
    float* fconst = (float*)((char*)d_ws + FPREP_BYTES);

    prep_filters<<<dim3(NFEAT * 4 + 1), dim3(256), 0, stream>>>(filt, bias, fprep, fconst);
    poly2d_mfma<<<dim3(256), dim3(512), 0, stream>>>(x, fprep, fconst, out);
}

// Round 7
// 36.486 us; speedup vs baseline: 2.2823x; 1.7477x over previous
//
#include <hip/hip_runtime.h>
#include <stdint.h>

#define HH 64
#define WW 64
#define PIN 64
#define POUT 64
#define NFEAT 54

typedef _Float16 half8 __attribute__((ext_vector_type(8)));
typedef _Float16 half4 __attribute__((ext_vector_type(4)));
typedef float f32x4 __attribute__((ext_vector_type(4)));
typedef float f32x16 __attribute__((ext_vector_type(16)));

// feature enumeration tables: f -> (k,l), matching prep_filters order
__constant__ const int KT[54] = {0,0,0,0,0,0,0,0,0, 1,1,1,1,1,1,1,1,1, 2,2,2,2,2,2,2,2,
                                 3,3,3,3,3,3,3, 4,4,4,4,4,4, 5,5,5,5,5, 6,6,6,6, 7,7,7, 8,8, 9};
__constant__ const int LT[54] = {1,2,3,4,5,6,7,8,9, 1,2,3,4,5,6,7,8,9, 2,3,4,5,6,7,8,9,
                                 3,4,5,6,7,8,9, 4,5,6,7,8,9, 5,6,7,8,9, 6,7,8,9, 7,8,9, 8,9, 9};

// ---------------- filter prep ----------------
__global__ void prep_filters(const float* __restrict__ f, const float* __restrict__ bias,
                             _Float16* __restrict__ fprep, float* __restrict__ fconst) {
    int blk = blockIdx.x;
    if (blk == NFEAT * 4) {
        int o = threadIdx.x;
        if (o < POUT) {
            float s = bias[o];
            for (int c = 0; c < PIN; ++c) s += f[(size_t)(o * PIN + c) * 100];
            fconst[o] = s;
        }
        return;
    }
    int feat = blk >> 2, part = blk & 3;
    int k = 0, l = 0, cnt = 0;
    for (int kk = 0; kk <= 9; ++kk) {
        int ls = (kk == 0) ? 1 : kk;
        for (int ll = ls; ll <= 9; ++ll) {
            if (cnt == feat) { k = kk; l = ll; }
            ++cnt;
        }
    }
    int iend = (part + 1) * 1024;
    for (int i = part * 1024 + threadIdx.x; i < iend; i += 256) {
        int o = i >> 6, c = i & 63;
        const float* fc = f + (size_t)(o * PIN + c) * 100;
        float v;
        if (k == 0)      v = fc[l] + fc[l * 10];
        else if (k == l) v = fc[k * 10 + k];
        else             v = fc[k * 10 + l] + fc[l * 10 + k];
        fprep[((size_t)feat * POUT + o) * PIN + c] = (_Float16)v;
    }
}

// barrier that the compiler cannot move memory ops across
__device__ __forceinline__ void blockbar() {
    asm volatile("" ::: "memory");
    __builtin_amdgcn_s_barrier();
    asm volatile("" ::: "memory");
}

// ---------------- main MFMA kernel ----------------
// 1024 thr = 16 waves = 4 m-tiles (32 px each: row hh, w-half) x 4 kc-quarters (K=16).
// MFMA 32x32x16_f16. B streamed via 3-slot LDS ring (global_load_lds, fragment-order
// chunks, counted vmcnt). kc partials reduced through LDS (x-region reuse).
__global__ __launch_bounds__(1024) void poly2d_mfma(
    const float* __restrict__ x, const _Float16* __restrict__ fprep,
    const float* __restrict__ fconst, float* __restrict__ out)
{
    __shared__ __align__(16) char smx[33792];   // x tile [4][66][8cg swz][16B]; reused as os[128][65] f32
    __shared__ __align__(16) char ring[3 * 8192]; // B ring, fragment-order 16B chunks

    const int t = threadIdx.x;
    const int lane = t & 63;
    const int wid = t >> 6;            // 0..15
    const int bid = blockIdx.x;
    const int b = bid >> 5;
    const int h0 = (bid & 31) * 2;

    // ---- stage x tile (rows h0-1..h0+2, w -1..64, all 64 c) as swizzled fp16 ----
    {
        const int w = t & 63;
        const int g = t >> 6;          // 0..15
        const int c = g * 4;           // channels c..c+3
        const int wl = w + 1;
        #pragma unroll
        for (int h = 0; h < 4; ++h) {
            int h_in = h0 - 1 + h;
            bool hok = ((unsigned)h_in < HH);
            float v0 = 0.f, v1 = 0.f, v2 = 0.f, v3 = 0.f;
            if (hok) {
                const float* gx = x + (((size_t)b * PIN + c) * HH + h_in) * WW + w;
                v0 = gx[0]; v1 = gx[4096]; v2 = gx[8192]; v3 = gx[12288];
            }
            half4 pk = {(_Float16)v0, (_Float16)v1, (_Float16)v2, (_Float16)v3};
            int byte = ((h * 66 + wl) * 8 + ((c >> 3) ^ (wl & 7))) * 16 + (c & 7) * 2;
            *(half4*)(smx + byte) = pk;
        }
        if (t < 64) { // w halo: wl=0 and wl=65 always out of image -> zero
            int h = t & 3, side = (t >> 2) & 1, cg = t >> 3;
            int wl2 = side ? 65 : 0;
            int byte = ((h * 66 + wl2) * 8 + (cg ^ (wl2 & 7))) * 16;
            f32x4 z = {0.f, 0.f, 0.f, 0.f};
            *(f32x4*)(smx + byte) = z;
        }
    }
    __syncthreads(); // drains vmcnt(0): clean baseline for manual counting

    const int kc = wid >> 2;           // 0..3 channel quarter
    const int mwid = wid & 3;          // m-tile: row hh = mwid>>1, w-half = mwid&1
    const int hh = mwid >> 1;
    const int wbase = (mwid & 1) * 32;
    const int l31 = lane & 31;
    const int lhi = lane >> 5;         // 0/1

    // stager (wid<8) source permutation: chunk p = wid*64+lane holds global bytes for
    // o = (lane&31) + ((wid&1)<<5), c-offset = ((wid>>1)&3)*16 halves + (lane>>5)*8 halves
    const int o_s = l31 + ((wid & 1) << 5);
    const int j16 = o_s * 128 + ((wid >> 1) & 3) * 32 + lhi * 16;
    const char* gsrc = (const char*)fprep + j16;

#define STAGE(ff)                                                                         \
    __builtin_amdgcn_global_load_lds(                                                     \
        (const __attribute__((address_space(1))) unsigned int*)(const void*)(gsrc + (size_t)(ff) * 8192), \
        (__attribute__((address_space(3))) unsigned int*)(void*)(ring + ((ff) % 3) * 8192 + (wid << 10)), \
        16, 0, 0)

    // prologue: stage features 0,1
    if (wid < 8) { STAGE(0); STAGE(1); }

    // ---- load 9 shift panels into registers (A-frag: row=lane&31 -> pixel, k=(lane>>5)*8+j) ----
    half8 xp[9];
    #pragma unroll
    for (int p = 1; p <= 9; ++p) {
        const int dh = (p - 1) / 3 - 1, dw = (p - 1) % 3 - 1;
        int wl = wbase + l31 + dw + 1;
        int hidx = hh + dh + 1;
        int cgl = kc * 2 + lhi;
        int byte = ((hidx * 66 + wl) * 8 + (cgl ^ (wl & 7))) * 16;
        xp[p - 1] = *(const half8*)(smx + byte);
    }

    f32x16 acc0 = {}, acc1 = {};

    #pragma unroll
    for (int f = 0; f < NFEAT; ++f) {
        // barrier 1: my reads of f-1 retired before anyone overwrites its slot
        asm volatile("s_waitcnt lgkmcnt(0)" ::: "memory");
        blockbar();
        if (f + 2 < NFEAT && wid < 8) { STAGE(f + 2); } // into slot (f+2)%3 = (f-1)%3
        // wait my chunk of feature f (counted, never drain in steady state)
        if (f < NFEAT - 2)       asm volatile("s_waitcnt vmcnt(2)" ::: "memory");
        else if (f == NFEAT - 2) asm volatile("s_waitcnt vmcnt(1)" ::: "memory");
        else                     asm volatile("s_waitcnt vmcnt(0)" ::: "memory");
        blockbar(); // barrier 2: whole tile f present

        const int k = KT[f], l = LT[f];
        const char* bbase = ring + (f % 3) * 8192 + (kc << 11) + (lane << 4);
        half8 b0 = *(const half8*)(bbase);
        half8 b1 = *(const half8*)(bbase + 1024);
        half8 a = (k == 0) ? xp[l - 1] : xp[k - 1] * xp[l - 1];
        acc0 = __builtin_amdgcn_mfma_f32_32x32x16_f16(a, b0, acc0, 0, 0, 0);
        acc1 = __builtin_amdgcn_mfma_f32_32x32x16_f16(a, b1, acc1, 0, 0, 0);
    }
#undef STAGE

    __syncthreads(); // loop done; x-region free for output staging
    float* os = (float*)smx; // [128 m][65]

    // reduce 4 kc partials (C/D: col=lane&31 (+nb*32), row=(r&3)+8*(r>>2)+4*(lane>>5))
    #pragma unroll
    for (int pass = 0; pass < 4; ++pass) {
        if (kc == pass) {
            #pragma unroll
            for (int nb = 0; nb < 2; ++nb) {
                #pragma unroll
                for (int r = 0; r < 16; ++r) {
                    int row = (r & 3) + 8 * (r >> 2) + 4 * lhi;
                    int m = mwid * 32 + row;
                    int col = l31 + nb * 32;
                    float v = nb ? acc1[r] : acc0[r];
                    if (pass == 0) os[m * 65 + col] = v;
                    else           os[m * 65 + col] += v;
                }
            }
        }
        __syncthreads();
    }

    { // coalesced store: lanes sweep w
        const int w = t & 63;
        const int og = t >> 6; // 0..15
        #pragma unroll
        for (int h2 = 0; h2 < 2; ++h2) {
            #pragma unroll
            for (int oo = 0; oo < 4; ++oo) {
                int o = og * 4 + oo;
                int m = (h2 * 2 + (w >> 5)) * 32 + (w & 31);
                float val = os[m * 65 + o] + fconst[o];
                out[(((size_t)b * POUT + o) * HH + (h0 + h2)) * WW + w] = val;
            }
        }
    }
}

// ---------------- fp32 fallback, used only if ws too small ----------------
__global__ __launch_bounds__(256) void poly2d_fp32(
    const float* __restrict__ x, const float* __restrict__ f,
    const float* __restrict__ bias, float* __restrict__ out)
{
    const int t = threadIdx.x;
    const int wo = t & 63;
    const int ho = (blockIdx.x & 15) * 4 + (t >> 6);
    const int o = (blockIdx.x >> 4) & 63;
    const int b = blockIdx.x >> 10;

    float acc = bias[o];
    const float* xb = x + (size_t)b * PIN * HH * WW;
    const float* fo = f + (size_t)o * PIN * 100;
    for (int c = 0; c < PIN; ++c) {
        const float* xc = xb + (size_t)c * HH * WW;
        float s[10];
        s[0] = 1.0f;
        #pragma unroll
        for (int kh = 0; kh < 3; ++kh) {
            int h = ho - 1 + kh;
            bool hok = ((unsigned)h < HH);
            #pragma unroll
            for (int kw = 0; kw < 3; ++kw) {
                int w = wo - 1 + kw;
                s[1 + kh * 3 + kw] = (hok && (unsigned)w < WW) ? xc[h * WW + w] : 0.0f;
            }
        }
        const float* fc = fo + c * 100;
        #pragma unroll
        for (int i = 0; i < 10; ++i) {
            float wsum = 0.0f;
            #pragma unroll
            for (int j = 0; j < 10; ++j) wsum = fmaf(fc[i * 10 + j], s[j], wsum);
            acc = fmaf(wsum, s[i], acc);
        }
    }
    out[(((size_t)b * POUT + o) * HH + ho) * WW + wo] = acc;
}

extern "C" void kernel_launch(void* const* d_in, const int* in_sizes, int n_in,
                              void* d_out, int out_size, void* d_ws, size_t ws_size,
                              hipStream_t stream) {
    const float* x    = (const float*)d_in[0];
    const float* filt = (const float*)d_in[1];
    const float* bias = (const float*)d_in[2];
    float* out = (float*)d_out;

    const size_t FPREP_BYTES = (size_t)NFEAT * POUT * PIN * 2; // 442368
    if (ws_size < FPREP_BYTES + 256) {
        poly2d_fp32<<<dim3(8 * 64 * 16), dim3(256), 0, stream>>>(x, filt, bias, out);
        return;
    }
    _Float16* fprep = (_Float16*)d_ws;
    float* fconst = (float*)((char*)d_ws + FPREP_BYTES);

    prep_filters<<<dim3(NFEAT * 4 + 1), dim3(256), 0, stream>>>(filt, bias, fprep, fconst);
    poly2d_mfma<<<dim3(256), dim3(1024), 0, stream>>>(x, fprep, fconst, out);
}